// Round 7
// baseline (751.136 us; speedup 1.0000x reference)
//
#include <hip/hip_runtime.h>
#include <math.h>

#define N_ 32
#define P_ 16
#define C_ 256
#define S_ 128
#define H_ 4
#define CLS_ 3000

typedef __attribute__((ext_vector_type(4))) float f4v;
typedef __attribute__((ext_vector_type(4))) float f32x4;
typedef __attribute__((ext_vector_type(8))) short short8;
typedef __attribute__((ext_vector_type(4))) unsigned short us4;

__device__ __forceinline__ unsigned short f2bf(float x){
    unsigned u = __float_as_uint(x);
    u += 0x7fffu + ((u >> 16) & 1u);
    return (unsigned short)(u >> 16);
}
__device__ __forceinline__ float bf2f(unsigned short h){
    return __uint_as_float(((unsigned)h) << 16);
}

// ---------------------------------------------------------------------------
// Split weights fp32 -> bf16 hi/lo (decay_w, qkv_w) and hi-only (out_w)
// ---------------------------------------------------------------------------
__global__ void wsplit(const float* __restrict__ dw, const float* __restrict__ qw,
                       const float* __restrict__ ow,
                       unsigned short* __restrict__ wdh, unsigned short* __restrict__ wdl,
                       unsigned short* __restrict__ wqh, unsigned short* __restrict__ wql,
                       unsigned short* __restrict__ woh){
    int i = blockIdx.x * 256 + threadIdx.x;
    int stride = gridDim.x * 256;
    for (; i < 3145728; i += stride){
        float a = dw[i]; unsigned short h = f2bf(a);
        wdh[i] = h; wdl[i] = f2bf(a - bf2f(h));
        float b = qw[i]; unsigned short h2 = f2bf(b);
        wqh[i] = h2; wql[i] = f2bf(b - bf2f(h2));
        if (i < 1048576) woh[i] = f2bf(ow[i]);
    }
}

// fc [256][3000] fp32 -> fcT [3072][256] bf16 (rows >= 3000 zeroed)
__global__ __launch_bounds__(256) void fct_kernel(const float* __restrict__ fc,
                                                  unsigned short* __restrict__ fcT){
    int n = blockIdx.x * 256 + threadIdx.x;   // 0..3071
    if (n < CLS_){
        for (int c = 0; c < 256; ++c) fcT[(size_t)n * 256 + c] = f2bf(fc[(size_t)c * CLS_ + n]);
    } else {
        for (int c = 0; c < 256; ++c) fcT[(size_t)n * 256 + c] = 0;
    }
}

// ---------------------------------------------------------------------------
// LDS-tiled transpose: x{H,L}[np_l][s][tsel*256+c] = split(t_x[np_g][c][s])
// ---------------------------------------------------------------------------
__global__ __launch_bounds__(256) void xT_kernel(
    const float* __restrict__ t_f, const float* __restrict__ t_s,
    const float* __restrict__ t_l,
    unsigned short* __restrict__ xH, unsigned short* __restrict__ xL, int n0){
    __shared__ float T[64 * 132];
    const int np_l = blockIdx.x, tsel = blockIdx.y;
    const float* src = (tsel == 0) ? t_f : ((tsel == 1) ? t_s : t_l);
    const size_t np_g = (size_t)(n0 * 16) + np_l;
    const float* sbase = src + np_g * 256 * 128;
    const size_t dbase = (size_t)np_l * 128 * 768 + tsel * 256;
    const int tid = threadIdx.x;
    const int so = tid & 127, ch = tid >> 7;   // write phase: row s, c-half

    for (int cp = 0; cp < 4; ++cp){
        const int c0 = cp * 64;
#pragma unroll
        for (int it = 0; it < 8; ++it){
            int f = tid + 256 * it;
            int c = f >> 5, s4 = (f & 31) << 2;
            *(f4v*)(T + c * 132 + s4) = *(const f4v*)(sbase + (size_t)(c0 + c) * 128 + s4);
        }
        __syncthreads();
        short8 Hh[4], Ll[4];
#pragma unroll
        for (int c8 = 0; c8 < 4; ++c8){
#pragma unroll
            for (int j = 0; j < 8; ++j){
                float v = T[(ch * 32 + c8 * 8 + j) * 132 + so];
                unsigned short hh = f2bf(v);
                Hh[c8][j] = (short)hh;
                Ll[c8][j] = (short)f2bf(v - bf2f(hh));
            }
        }
        size_t dr = dbase + (size_t)so * 768 + c0 + ch * 32;
#pragma unroll
        for (int c8 = 0; c8 < 4; ++c8){
            *(short8*)(xH + dr + c8 * 8) = Hh[c8];
            *(short8*)(xL + dr + c8 * 8) = Ll[c8];
        }
        __syncthreads();
    }
}

// ---------------------------------------------------------------------------
// Split-bf16 MFMA GEMM, LDS-free K-loop:  D[s][o] = sum_k A[s][k] * W[o][k]
// Each wave loads A/B fragments directly global->VGPR (no K-loop barriers).
// MODE 0/1 (3-term): hi/lo bf16 plane outputs via LDS-transpose epilogue
//   (pitch 136, full 128-col coverage — fixed from round 6).
// MODE 2 (1-term): wpv epilogue (residual + max over s).
// ---------------------------------------------------------------------------
template<int KEXT, int APITCH, int ND, int MODE, int OPITCH>
__global__ __launch_bounds__(256) void gemm3(
    const unsigned short* __restrict__ Ah_g, const unsigned short* __restrict__ Al_g,
    const unsigned short* __restrict__ Whi, const unsigned short* __restrict__ Wlo,
    const unsigned short* __restrict__ resH, const unsigned short* __restrict__ resL,
    unsigned short* __restrict__ outH, unsigned short* __restrict__ outL,
    float* __restrict__ outF, int n0)
{
    constexpr int T3 = (MODE == 2) ? 0 : 1;
    __shared__ unsigned short Ep[(MODE != 2) ? 128 * 136 : 64];
    __shared__ float cmax[2][2][64];

    const int tid = threadIdx.x;
    const int w = tid >> 6, l = tid & 63;
    const int lr = l & 15, lg = l >> 4;
    const int ws0 = (w & 1) * 64, wo0 = (w >> 1) * 64;
    const int o0 = blockIdx.x * 128;
    const int np_l = blockIdx.y;
    const int p = np_l & 15;

    const size_t aOff = (size_t)np_l * 128 * APITCH + (size_t)(ws0 + lr) * APITCH + lg * 8;
    const unsigned short* Ath = Ah_g + aOff;
    const unsigned short* Atl = Al_g + aOff;
    const size_t bOff = ((size_t)p * ND + o0 + wo0 + lr) * KEXT + lg * 8;
    const unsigned short* Bth = Whi + bOff;
    const unsigned short* Btl = Wlo + bOff;

    f32x4 acc[4][4];
#pragma unroll
    for (int i = 0; i < 4; ++i)
#pragma unroll
        for (int j = 0; j < 4; ++j) acc[i][j] = (f32x4){0.f, 0.f, 0.f, 0.f};

#pragma unroll 4
    for (int k0 = 0; k0 < KEXT; k0 += 32){
        short8 ah[4], bh[4], al[4], bl[4];
#pragma unroll
        for (int sf = 0; sf < 4; ++sf){
            ah[sf] = *(const short8*)(Ath + sf * 16 * APITCH + k0);
            if (T3) al[sf] = *(const short8*)(Atl + sf * 16 * APITCH + k0);
        }
#pragma unroll
        for (int of = 0; of < 4; ++of){
            bh[of] = *(const short8*)(Bth + of * 16 * KEXT + k0);
            if (T3) bl[of] = *(const short8*)(Btl + of * 16 * KEXT + k0);
        }
#pragma unroll
        for (int of = 0; of < 4; ++of){
#pragma unroll
            for (int sf = 0; sf < 4; ++sf){
                acc[sf][of] = __builtin_amdgcn_mfma_f32_16x16x32_bf16(ah[sf], bh[of], acc[sf][of], 0, 0, 0);
                if (T3){
                    acc[sf][of] = __builtin_amdgcn_mfma_f32_16x16x32_bf16(ah[sf], bl[of], acc[sf][of], 0, 0, 0);
                    acc[sf][of] = __builtin_amdgcn_mfma_f32_16x16x32_bf16(al[sf], bh[of], acc[sf][of], 0, 0, 0);
                }
            }
        }
    }

    if (MODE != 2){
        // LDS-transpose epilogue: coalesced full-line short8 stores, 2 planes
#pragma unroll
        for (int plane = 0; plane < 2; ++plane){
#pragma unroll
            for (int sf = 0; sf < 4; ++sf)
#pragma unroll
                for (int of = 0; of < 4; ++of){
                    int col = wo0 + of * 16 + lr;
#pragma unroll
                    for (int r = 0; r < 4; ++r){
                        int row = ws0 + sf * 16 + lg * 4 + r;
                        float v = acc[sf][of][r];
                        unsigned short hh = f2bf(v);
                        unsigned short q = plane ? f2bf(v - bf2f(hh)) : hh;
                        Ep[row * 136 + col] = q;
                    }
                }
            __syncthreads();
            unsigned short* dst = plane ? outL : outH;
#pragma unroll
            for (int it = 0; it < 8; ++it){
                int idx = tid + 256 * it;
                int row = idx >> 4, seg = (idx & 15) * 8;
                *(short8*)(dst + (size_t)np_l * 128 * OPITCH + (size_t)row * OPITCH + o0 + seg) =
                    *(const short8*)(Ep + row * 136 + seg);
            }
            __syncthreads();
        }
    } else {
        const int n_g = n0 + (np_l >> 4);
#pragma unroll
        for (int of = 0; of < 4; ++of){
            int oc = o0 + wo0 + of * 16 + lr;
            float m = -INFINITY;
#pragma unroll
            for (int sf = 0; sf < 4; ++sf){
#pragma unroll
                for (int r = 0; r < 4; ++r){
                    int s = ws0 + sf * 16 + lg * 4 + r;
                    size_t ri = (size_t)np_l * 128 * 256 + (size_t)s * 256 + oc;
                    float v = acc[sf][of][r] + bf2f(resH[ri]) + bf2f(resL[ri]);
                    m = fmaxf(m, v);
                }
            }
            m = fmaxf(m, __shfl_xor(m, 16));
            m = fmaxf(m, __shfl_xor(m, 32));
            if (l < 16) cmax[w >> 1][w & 1][of * 16 + l] = m;
        }
        __syncthreads();
        if (tid < 128){
            int oh = tid >> 6, col = tid & 63;
            float v = fmaxf(cmax[oh][0][col], cmax[oh][1][col]);
            outF[((size_t)p * N_ + n_g) * C_ + o0 + oh * 64 + col] = v;
        }
    }
}

// ---------------------------------------------------------------------------
// Attention per (n,h,p): 3-term split QK^T MFMA (bf16 plane inputs),
// fp32 softmax+colsum (argmax), bf16 PV MFMA; O (bf16 hi) overwrites q-cols.
// ---------------------------------------------------------------------------
__global__ __launch_bounds__(256) void attn3(unsigned short* __restrict__ qH,
                                             const unsigned short* __restrict__ qL,
                                             int* __restrict__ idxA, int n0){
    __shared__ char smraw[17408 + 34816 + 2048];
    unsigned short* Vs = (unsigned short*)smraw;             // [64][136] bf16
    unsigned short* Pm = (unsigned short*)(smraw + 17408);   // [128][136] bf16
    float* csW = (float*)(smraw + 17408 + 34816);            // [4][128]
    unsigned short* Ot = (unsigned short*)smraw;             // [128][72] bf16 (alias)

    const int b = blockIdx.x;
    const int n_l = b >> 6, h = (b >> 4) & 3, p = b & 15;
    const int np_l = n_l * 16 + p;
    const int tid = threadIdx.x, w = tid >> 6, l = tid & 63;
    const int lr = l & 15, lg = l >> 4;
    unsigned short* baseH = qH + (size_t)np_l * 128 * 768;
    const unsigned short* baseL = qL + (size_t)np_l * 128 * 768;

    // stage V: bf16 [t][d] -> Vs[d][t]
#pragma unroll
    for (int it = 0; it < 8; ++it){
        int idx = tid + 256 * it;
        int t = idx >> 4, d4 = (idx & 15) * 4;
        us4 v = *(const us4*)(baseH + (size_t)t * 768 + 512 + h * 64 + d4);
#pragma unroll
        for (int j = 0; j < 4; ++j) Vs[(d4 + j) * 136 + t] = v[j];
    }

    // Q fragments (hi/lo) straight from planes
    short8 qh[2][2], ql[2][2];
#pragma unroll
    for (int sf = 0; sf < 2; ++sf)
#pragma unroll
        for (int ks = 0; ks < 2; ++ks){
            size_t off = (size_t)(w * 32 + sf * 16 + lr) * 768 + h * 64 + ks * 32 + lg * 8;
            qh[sf][ks] = *(const short8*)(baseH + off);
            ql[sf][ks] = *(const short8*)(baseL + off);
        }

    f32x4 dacc[2][8];
#pragma unroll
    for (int i = 0; i < 2; ++i)
#pragma unroll
        for (int j = 0; j < 8; ++j) dacc[i][j] = (f32x4){0.f, 0.f, 0.f, 0.f};

#pragma unroll
    for (int tf = 0; tf < 8; ++tf){
#pragma unroll
        for (int ks = 0; ks < 2; ++ks){
            size_t off = (size_t)(tf * 16 + lr) * 768 + 256 + h * 64 + ks * 32 + lg * 8;
            short8 kh = *(const short8*)(baseH + off);
            short8 kl = *(const short8*)(baseL + off);
#pragma unroll
            for (int sf = 0; sf < 2; ++sf){
                dacc[sf][tf] = __builtin_amdgcn_mfma_f32_16x16x32_bf16(qh[sf][ks], kh, dacc[sf][tf], 0, 0, 0);
                dacc[sf][tf] = __builtin_amdgcn_mfma_f32_16x16x32_bf16(qh[sf][ks], kl, dacc[sf][tf], 0, 0, 0);
                dacc[sf][tf] = __builtin_amdgcn_mfma_f32_16x16x32_bf16(ql[sf][ks], kh, dacc[sf][tf], 0, 0, 0);
            }
        }
    }

    // softmax + write P bf16 + fp32 colsum partials
    float csp[8];
#pragma unroll
    for (int tf = 0; tf < 8; ++tf) csp[tf] = 0.f;
#pragma unroll
    for (int sf = 0; sf < 2; ++sf){
#pragma unroll
        for (int r = 0; r < 4; ++r){
            float m = -INFINITY;
#pragma unroll
            for (int tf = 0; tf < 8; ++tf) m = fmaxf(m, dacc[sf][tf][r]);
            m = fmaxf(m, __shfl_xor(m, 1)); m = fmaxf(m, __shfl_xor(m, 2));
            m = fmaxf(m, __shfl_xor(m, 4)); m = fmaxf(m, __shfl_xor(m, 8));
            float e[8]; float sum = 0.f;
#pragma unroll
            for (int tf = 0; tf < 8; ++tf){
                e[tf] = __expf(0.125f * (dacc[sf][tf][r] - m)); sum += e[tf];
            }
            sum += __shfl_xor(sum, 1); sum += __shfl_xor(sum, 2);
            sum += __shfl_xor(sum, 4); sum += __shfl_xor(sum, 8);
            float inv = 1.f / sum;
            int s = w * 32 + sf * 16 + lg * 4 + r;
#pragma unroll
            for (int tf = 0; tf < 8; ++tf){
                float pv = e[tf] * inv;
                Pm[s * 136 + tf * 16 + lr] = f2bf(pv);
                csp[tf] += pv;
            }
        }
    }
#pragma unroll
    for (int tf = 0; tf < 8; ++tf){
        float v = csp[tf];
        v += __shfl_xor(v, 16); v += __shfl_xor(v, 32);
        if (l < 16) csW[w * 128 + tf * 16 + l] = v;
    }
    __syncthreads();

    // PV: D[d][s] = sum_t V[d][t] P[s][t]
    f32x4 oacc[8];
#pragma unroll
    for (int i = 0; i < 8; ++i) oacc[i] = (f32x4){0.f, 0.f, 0.f, 0.f};
#pragma unroll
    for (int ks = 0; ks < 4; ++ks){
        short8 av = *(const short8*)(Vs + (w * 16 + lr) * 136 + ks * 32 + lg * 8);
#pragma unroll
        for (int sf = 0; sf < 8; ++sf){
            short8 bp = *(const short8*)(Pm + (sf * 16 + lr) * 136 + ks * 32 + lg * 8);
            oacc[sf] = __builtin_amdgcn_mfma_f32_16x16x32_bf16(av, bp, oacc[sf], 0, 0, 0);
        }
    }
    __syncthreads();

    // argmax of colsum (fp32) — first occurrence
    if (tid < 64){
        float v0 = csW[tid] + csW[128 + tid] + csW[256 + tid] + csW[384 + tid];
        float v1 = csW[64 + tid] + csW[192 + tid] + csW[320 + tid] + csW[448 + tid];
        float bv; int bi;
        if (v1 > v0){ bv = v1; bi = 64 + tid; } else { bv = v0; bi = tid; }
#pragma unroll
        for (int msk = 1; msk <= 32; msk <<= 1){
            float ov = __shfl_xor(bv, msk); int oi = __shfl_xor(bi, msk);
            if (ov > bv || (ov == bv && oi < bi)){ bv = ov; bi = oi; }
        }
        if (tid == 0){ int n_g = n0 + n_l; idxA[(n_g * H_ + h) * P_ + p] = bi; }
    }

    // O frags -> Ot[s][d] bf16, then coalesced store over q-cols (hi plane)
#pragma unroll
    for (int sf = 0; sf < 8; ++sf){
        int s = sf * 16 + lr;
#pragma unroll
        for (int r = 0; r < 4; ++r) Ot[s * 72 + w * 16 + lg * 4 + r] = f2bf(oacc[sf][r]);
    }
    __syncthreads();
#pragma unroll
    for (int it = 0; it < 4; ++it){
        int idx = tid + 256 * it;
        int s = idx >> 3, d8 = (idx & 7) * 8;
        *(short8*)(baseH + (size_t)s * 768 + h * 64 + d8) = *(const short8*)(Ot + s * 72 + d8);
    }
}

// ---------------------------------------------------------------------------
__global__ void bn_stats(const float* __restrict__ wpvT,
                         const float* __restrict__ gamma,
                         const float* __restrict__ beta,
                         float* __restrict__ aArr, float* __restrict__ bArr)
{
    int i = blockIdx.x * blockDim.x + threadIdx.x;
    if (i >= P_ * C_) return;
    int p = i / C_, c = i % C_;
    const float* basep = wpvT + (size_t)p * N_ * C_ + c;
    float su = 0.f, s2 = 0.f;
    for (int n = 0; n < N_; ++n){
        float v = basep[n * C_];
        su += v; s2 += v * v;
    }
    float mean = su * (1.f / N_);
    float var = s2 * (1.f / N_) - mean * mean;
    float rstd = rsqrtf(var + 1e-5f);
    float a = gamma[i] * rstd;
    aArr[i] = a;
    bArr[i] = beta[i] - mean * a;
}

// pf[m][c] = bf16(wpvT[m][c]*a + b), m = p*32+n
__global__ __launch_bounds__(256) void pf_kernel(const float* __restrict__ wpvT,
                                                 const float* __restrict__ aArr,
                                                 const float* __restrict__ bArr,
                                                 unsigned short* __restrict__ pfb){
    int m = blockIdx.x, c = threadIdx.x;
    int p = m >> 5;
    float v = wpvT[(size_t)m * 256 + c];
    pfb[(size_t)m * 256 + c] = f2bf(v * aArr[p * 256 + c] + bArr[p * 256 + c]);
}

// cls GEMM: cls[n*16+p][k] = sum_c pf[p*32+n][c] * fcT[k][c]; 1-term bf16
__global__ __launch_bounds__(256) void gemmc(const unsigned short* __restrict__ pfb,
                                             const unsigned short* __restrict__ fcT,
                                             float* __restrict__ cls){
    __shared__ unsigned short sm[2 * 128 * 72];
    unsigned short* AhL = sm;
    unsigned short* BhL = sm + 128 * 72;

    const int tid = threadIdx.x;
    const int w = tid >> 6, l = tid & 63;
    const int lr = l & 15, lg = l >> 4;
    const int ws0 = (w & 1) * 64, wo0 = (w >> 1) * 64;
    const int o0 = blockIdx.x * 128;
    const int m0 = blockIdx.y * 128;

    f32x4 acc[4][4];
#pragma unroll
    for (int i = 0; i < 4; ++i)
#pragma unroll
        for (int j = 0; j < 4; ++j) acc[i][j] = (f32x4){0.f, 0.f, 0.f, 0.f};

    for (int k0 = 0; k0 < 256; k0 += 64){
#pragma unroll
        for (int it = 0; it < 4; ++it){
            int idx = tid + 256 * it;
            int s = idx >> 3, c8 = (idx & 7) * 8;
            *(short8*)(AhL + s * 72 + c8) = *(const short8*)(pfb + (size_t)(m0 + s) * 256 + k0 + c8);
            *(short8*)(BhL + s * 72 + c8) = *(const short8*)(fcT + (size_t)(o0 + s) * 256 + k0 + c8);
        }
        __syncthreads();
#pragma unroll
        for (int ks = 0; ks < 2; ++ks){
            short8 ah[4];
#pragma unroll
            for (int sf = 0; sf < 4; ++sf)
                ah[sf] = *(const short8*)(AhL + (ws0 + sf * 16 + lr) * 72 + ks * 32 + lg * 8);
#pragma unroll
            for (int of = 0; of < 4; ++of){
                short8 bh = *(const short8*)(BhL + (wo0 + of * 16 + lr) * 72 + ks * 32 + lg * 8);
#pragma unroll
                for (int sf = 0; sf < 4; ++sf)
                    acc[sf][of] = __builtin_amdgcn_mfma_f32_16x16x32_bf16(ah[sf], bh, acc[sf][of], 0, 0, 0);
            }
        }
        __syncthreads();
    }
#pragma unroll
    for (int sf = 0; sf < 4; ++sf)
#pragma unroll
        for (int of = 0; of < 4; ++of){
            int oc = o0 + wo0 + of * 16 + lr;
            if (oc < CLS_){
#pragma unroll
                for (int r = 0; r < 4; ++r){
                    int m = m0 + ws0 + sf * 16 + lg * 4 + r;
                    int n = m & 31, p = m >> 5;
                    cls[((size_t)n * 16 + p) * CLS_ + oc] = acc[sf][of][r];
                }
            }
        }
}

__global__ void sel_kernel(const float* __restrict__ t_f,
                           const int* __restrict__ idxArr,
                           float* __restrict__ selT)
{
    const int np = blockIdx.x;
    const int n = np >> 4, p = np & 15;
    const int c = threadIdx.x;
    float acc = 0.f;
#pragma unroll
    for (int h = 0; h < H_; ++h){
        int s = idxArr[(n * H_ + h) * P_ + p];
        acc += t_f[((size_t)np * C_ + c) * S_ + s];
    }
    selT[((size_t)p * N_ + n) * C_ + c] = acc;
}

// ---------------------------------------------------------------------------
extern "C" void kernel_launch(void* const* d_in, const int* in_sizes, int n_in,
                              void* d_out, int out_size, void* d_ws, size_t ws_size,
                              hipStream_t stream)
{
    const float* t_f     = (const float*)d_in[0];
    const float* t_s     = (const float*)d_in[1];
    const float* t_l     = (const float*)d_in[2];
    const float* decay_w = (const float*)d_in[3];
    const float* qkv_w   = (const float*)d_in[4];
    const float* out_w   = (const float*)d_in[5];
    const float* gamma   = (const float*)d_in[6];
    const float* beta    = (const float*)d_in[7];
    const float* fc      = (const float*)d_in[8];
    float* out = (float*)d_out;

    // ---- ws layout: converted weights at head, then chunked activations ----
    const size_t WD = 3145728, WQ = 3145728, WO = 1048576;
    char* basep = (char*)d_ws;
    unsigned short* wdh = (unsigned short*)basep;
    unsigned short* wdl = wdh + WD;
    unsigned short* wqh = wdl + WD;
    unsigned short* wql = wqh + WQ;
    unsigned short* woh = wql + WQ;
    unsigned short* fcT = woh + WO;            // 3072*256
    unsigned short* pfb = fcT + 3072 * 256;    // 512*256
    float* aArr = (float*)(pfb + 512 * 256);
    float* bArr = aArr + P_ * C_;
    int* idxA = (int*)(bArr + P_ * C_);
    char* big = (char*)(idxA + N_ * H_ * P_);
    size_t head = (size_t)(big - basep);
    size_t avail = (ws_size > head) ? (ws_size - head) : 0;
    const size_t per_n = (size_t)16 * 128 * (768 + 256 + 768) * 2 * 2;  // hi+lo bf16
    int cn = (int)(avail / per_n);
    if (cn < 1) cn = 1;
    if (cn > N_) cn = N_;
    int nch = (N_ + cn - 1) / cn;
    cn = (N_ + nch - 1) / nch;

    unsigned short* xH = (unsigned short*)big;                 // cn*16*128*768
    unsigned short* xL = xH + (size_t)cn * 16 * 128 * 768;
    unsigned short* tH = xL + (size_t)cn * 16 * 128 * 768;     // cn*16*128*256
    unsigned short* tL = tH + (size_t)cn * 16 * 128 * 256;
    unsigned short* qH = tL + (size_t)cn * 16 * 128 * 256;     // cn*16*128*768
    unsigned short* qL = qH + (size_t)cn * 16 * 128 * 768;

    float* cls  = out;
    float* wpvT = out + (size_t)N_ * P_ * CLS_;
    float* selT = wpvT + (size_t)P_ * N_ * C_;

    wsplit<<<2048, 256, 0, stream>>>(decay_w, qkv_w, out_w, wdh, wdl, wqh, wql, woh);
    fct_kernel<<<12, 256, 0, stream>>>(fc, fcT);

    for (int n0 = 0; n0 < N_; n0 += cn){
        int c = (N_ - n0 < cn) ? (N_ - n0) : cn;
        int npg = c * 16;
        xT_kernel<<<dim3(npg, 3), 256, 0, stream>>>(t_f, t_s, t_l, xH, xL, n0);
        gemm3<768, 768, 256, 0, 256><<<dim3(2, npg), 256, 0, stream>>>(
            xH, xL, wdh, wdl, nullptr, nullptr, tH, tL, nullptr, n0);
        gemm3<256, 256, 768, 1, 768><<<dim3(6, npg), 256, 0, stream>>>(
            tH, tL, wqh, wql, nullptr, nullptr, qH, qL, nullptr, n0);
        attn3<<<dim3(c * 64), 256, 0, stream>>>(qH, qL, idxA, n0);
        gemm3<256, 768, 256, 2, 256><<<dim3(2, npg), 256, 0, stream>>>(
            qH, qH, woh, woh, tH, tL, nullptr, nullptr, wpvT, n0);
    }
    bn_stats<<<(P_ * C_ + 255) / 256, 256, 0, stream>>>(wpvT, gamma, beta, aArr, bArr);
    pf_kernel<<<512, 256, 0, stream>>>(wpvT, aArr, bArr, pfb);
    gemmc<<<dim3(24, 4), 256, 0, stream>>>(pfb, fcT, cls);
    sel_kernel<<<N_ * P_, 256, 0, stream>>>(t_f, idxA, selT);
}

// Round 8
// 522.787 us; speedup vs baseline: 1.4368x; 1.4368x over previous
//
#include <hip/hip_runtime.h>
#include <math.h>

#define N_ 32
#define P_ 16
#define C_ 256
#define S_ 128
#define H_ 4
#define CLS_ 3000

typedef __attribute__((ext_vector_type(4))) float f4v;
typedef __attribute__((ext_vector_type(4))) float f32x4;
typedef __attribute__((ext_vector_type(8))) short short8;
typedef __attribute__((ext_vector_type(4))) unsigned short us4;

__device__ __forceinline__ unsigned short f2bf(float x){
    unsigned u = __float_as_uint(x);
    u += 0x7fffu + ((u >> 16) & 1u);
    return (unsigned short)(u >> 16);
}
__device__ __forceinline__ float bf2f(unsigned short h){
    return __uint_as_float(((unsigned)h) << 16);
}

typedef __attribute__((address_space(1))) const unsigned int gu32_t;
typedef __attribute__((address_space(3))) unsigned int lu32_t;
__device__ __forceinline__ void gload16(const void* g, void* l){
    __builtin_amdgcn_global_load_lds((gu32_t*)g, (lu32_t*)l, 16, 0, 0);
}

// ---------------------------------------------------------------------------
// Split weights fp32 -> bf16 hi/lo (decay_w, qkv_w) and hi-only (out_w)
// ---------------------------------------------------------------------------
__global__ void wsplit(const float* __restrict__ dw, const float* __restrict__ qw,
                       const float* __restrict__ ow,
                       unsigned short* __restrict__ wdh, unsigned short* __restrict__ wdl,
                       unsigned short* __restrict__ wqh, unsigned short* __restrict__ wql,
                       unsigned short* __restrict__ woh){
    int i = blockIdx.x * 256 + threadIdx.x;
    int stride = gridDim.x * 256;
    for (; i < 3145728; i += stride){
        float a = dw[i]; unsigned short h = f2bf(a);
        wdh[i] = h; wdl[i] = f2bf(a - bf2f(h));
        float b = qw[i]; unsigned short h2 = f2bf(b);
        wqh[i] = h2; wql[i] = f2bf(b - bf2f(h2));
        if (i < 1048576) woh[i] = f2bf(ow[i]);
    }
}

// fc [256][3000] fp32 -> fcT [3072][256] bf16 (rows >= 3000 zeroed)
__global__ __launch_bounds__(256) void fct_kernel(const float* __restrict__ fc,
                                                  unsigned short* __restrict__ fcT){
    int n = blockIdx.x * 256 + threadIdx.x;   // 0..3071
    if (n < CLS_){
        for (int c = 0; c < 256; ++c) fcT[(size_t)n * 256 + c] = f2bf(fc[(size_t)c * CLS_ + n]);
    } else {
        for (int c = 0; c < 256; ++c) fcT[(size_t)n * 256 + c] = 0;
    }
}

// ---------------------------------------------------------------------------
// LDS-tiled transpose: x{H,L}[np_l][s][tsel*256+c] = split(t_x[np_g][c][s])
// ---------------------------------------------------------------------------
__global__ __launch_bounds__(256) void xT_kernel(
    const float* __restrict__ t_f, const float* __restrict__ t_s,
    const float* __restrict__ t_l,
    unsigned short* __restrict__ xH, unsigned short* __restrict__ xL, int n0){
    __shared__ float T[64 * 132];
    const int np_l = blockIdx.x, tsel = blockIdx.y;
    const float* src = (tsel == 0) ? t_f : ((tsel == 1) ? t_s : t_l);
    const size_t np_g = (size_t)(n0 * 16) + np_l;
    const float* sbase = src + np_g * 256 * 128;
    const size_t dbase = (size_t)np_l * 128 * 768 + tsel * 256;
    const int tid = threadIdx.x;
    const int so = tid & 127, ch = tid >> 7;   // write phase: row s, c-half

    for (int cp = 0; cp < 4; ++cp){
        const int c0 = cp * 64;
#pragma unroll
        for (int it = 0; it < 8; ++it){
            int f = tid + 256 * it;
            int c = f >> 5, s4 = (f & 31) << 2;
            *(f4v*)(T + c * 132 + s4) = *(const f4v*)(sbase + (size_t)(c0 + c) * 128 + s4);
        }
        __syncthreads();
        short8 Hh[4], Ll[4];
#pragma unroll
        for (int c8 = 0; c8 < 4; ++c8){
#pragma unroll
            for (int j = 0; j < 8; ++j){
                float v = T[(ch * 32 + c8 * 8 + j) * 132 + so];
                unsigned short hh = f2bf(v);
                Hh[c8][j] = (short)hh;
                Ll[c8][j] = (short)f2bf(v - bf2f(hh));
            }
        }
        size_t dr = dbase + (size_t)so * 768 + c0 + ch * 32;
#pragma unroll
        for (int c8 = 0; c8 < 4; ++c8){
            *(short8*)(xH + dr + c8 * 8) = Hh[c8];
            *(short8*)(xL + dr + c8 * 8) = Ll[c8];
        }
        __syncthreads();
    }
}

// ---------------------------------------------------------------------------
// Split-bf16 MFMA GEMM (round-5 K-loop):  D[s][o] = sum_k A[s][k] * W[o][k]
// Staging: global_load_lds(16) into linear [128][64]-short tiles, 16B-chunk
// XOR-swizzled by (row&7) on the SOURCE address; frag reads apply same XOR.
// Flat grid, XCD-swizzled: each XCD owns parts {2x,2x+1}; all o-tiles of an
// np stay on one XCD (A stays L2-resident; per-XCD weight slice L2-resident).
// MODE 0/1 (3-term): hi/lo planes via pitch-136 LDS-transpose epilogue
//   (Ep aliases the staging LDS; barrier-protected).
// MODE 2 (1-term): wpv epilogue (residual + max over s).
// ---------------------------------------------------------------------------
template<int KEXT, int APITCH, int ND, int MODE, int OPITCH>
__global__ __launch_bounds__(256) void gemm3(
    const unsigned short* __restrict__ Ah_g, const unsigned short* __restrict__ Al_g,
    const unsigned short* __restrict__ Whi, const unsigned short* __restrict__ Wlo,
    const unsigned short* __restrict__ resH, const unsigned short* __restrict__ resL,
    unsigned short* __restrict__ outH, unsigned short* __restrict__ outL,
    float* __restrict__ outF, int n0, int cnp)
{
    constexpr int T3 = (MODE == 2) ? 0 : 1;
    constexpr int OB = ND / 128;
    __shared__ unsigned short sm[(T3 ? 4 : 2) * 128 * 64];
    unsigned short* AhL = sm;
    unsigned short* BhL = sm + 8192;
    unsigned short* AlL = T3 ? (sm + 16384) : sm;
    unsigned short* BlL = T3 ? (sm + 24576) : sm;
    unsigned short* Ep = sm;   // epilogue alias (34816 B <= 65536 B, T3 only)
    __shared__ float cmax[2][2][64];

    // --- XCD-aware flat-grid mapping ---
    const int id = blockIdx.x;
    const int xcd = id & 7;
    const int r = id >> 3;               // 0 .. 2*cnp*OB - 1
    const int ppl = r / (cnp * OB);
    const int rr = r % (cnp * OB);
    const int n_l = rr / OB;
    const int o_t = rr % OB;
    const int p = xcd * 2 + ppl;
    const int np_l = n_l * 16 + p;
    const int o0 = o_t * 128;

    const int tid = threadIdx.x;
    const int w = tid >> 6, l = tid & 63;
    const int lr = l & 15, lg = l >> 4;
    const int ws0 = (w & 1) * 64, wo0 = (w >> 1) * 64;
    const size_t aBase = (size_t)np_l * 128 * APITCH;
    const unsigned short* Wp_h = Whi + ((size_t)p * ND + o0) * KEXT;
    const unsigned short* Wp_l = T3 ? (Wlo + ((size_t)p * ND + o0) * KEXT) : Wp_h;

    f32x4 acc[4][4];
#pragma unroll
    for (int i = 0; i < 4; ++i)
#pragma unroll
        for (int j = 0; j < 4; ++j) acc[i][j] = (f32x4){0.f, 0.f, 0.f, 0.f};

    for (int k0 = 0; k0 < KEXT; k0 += 64){
        // --- async staging: 1024B per wave-inst; lane lin = slot*64 + l ---
#pragma unroll
        for (int it = 0; it < 4; ++it){
            int slot = w * 4 + it;
            int lin = slot * 64 + l;
            int row = lin >> 3, chnk = lin & 7;
            int sk = ((chnk ^ (row & 7)) << 3);
            unsigned short* ldst = sm + slot * 512;  // shorts; +8192*plane below
            const unsigned short* ga = Ah_g + aBase + (size_t)row * APITCH + k0 + sk;
            gload16(ga, ldst);
            const unsigned short* gb = Wp_h + (size_t)row * KEXT + k0 + sk;
            gload16(gb, ldst + 8192);
            if (T3){
                gload16(Al_g + aBase + (size_t)row * APITCH + k0 + sk, ldst + 16384);
                gload16(Wp_l + (size_t)row * KEXT + k0 + sk, ldst + 24576);
            }
        }
        __syncthreads();
#pragma unroll
        for (int ks = 0; ks < 2; ++ks){
            short8 ah[4], al[4];
#pragma unroll
            for (int sf = 0; sf < 4; ++sf){
                int row = ws0 + sf * 16 + lr;
                int cof = ((ks * 4 + lg) ^ (row & 7)) << 3;
                ah[sf] = *(const short8*)(AhL + row * 64 + cof);
                if (T3) al[sf] = *(const short8*)(AlL + row * 64 + cof);
            }
#pragma unroll
            for (int of = 0; of < 4; ++of){
                int row = wo0 + of * 16 + lr;
                int cof = ((ks * 4 + lg) ^ (row & 7)) << 3;
                short8 bh = *(const short8*)(BhL + row * 64 + cof);
                short8 bl = bh;
                if (T3) bl = *(const short8*)(BlL + row * 64 + cof);
#pragma unroll
                for (int sf = 0; sf < 4; ++sf){
                    acc[sf][of] = __builtin_amdgcn_mfma_f32_16x16x32_bf16(ah[sf], bh, acc[sf][of], 0, 0, 0);
                    if (T3){
                        acc[sf][of] = __builtin_amdgcn_mfma_f32_16x16x32_bf16(ah[sf], bl, acc[sf][of], 0, 0, 0);
                        acc[sf][of] = __builtin_amdgcn_mfma_f32_16x16x32_bf16(al[sf], bh, acc[sf][of], 0, 0, 0);
                    }
                }
            }
        }
        __syncthreads();
    }

    if (MODE != 2){
        // LDS-transpose epilogue (Ep aliases sm; K-loop ended with barrier)
#pragma unroll
        for (int plane = 0; plane < 2; ++plane){
#pragma unroll
            for (int sf = 0; sf < 4; ++sf)
#pragma unroll
                for (int of = 0; of < 4; ++of){
                    int col = wo0 + of * 16 + lr;
#pragma unroll
                    for (int r2 = 0; r2 < 4; ++r2){
                        int row = ws0 + sf * 16 + lg * 4 + r2;
                        float v = acc[sf][of][r2];
                        unsigned short hh = f2bf(v);
                        unsigned short q = plane ? f2bf(v - bf2f(hh)) : hh;
                        Ep[row * 136 + col] = q;
                    }
                }
            __syncthreads();
            unsigned short* dst = plane ? outL : outH;
#pragma unroll
            for (int it = 0; it < 8; ++it){
                int idx = tid + 256 * it;
                int row = idx >> 4, seg = (idx & 15) * 8;
                *(short8*)(dst + (size_t)np_l * 128 * OPITCH + (size_t)row * OPITCH + o0 + seg) =
                    *(const short8*)(Ep + row * 136 + seg);
            }
            __syncthreads();
        }
    } else {
        const int n_g = n0 + n_l;
#pragma unroll
        for (int of = 0; of < 4; ++of){
            int oc = o0 + wo0 + of * 16 + lr;
            float m = -INFINITY;
#pragma unroll
            for (int sf = 0; sf < 4; ++sf){
#pragma unroll
                for (int r2 = 0; r2 < 4; ++r2){
                    int s = ws0 + sf * 16 + lg * 4 + r2;
                    size_t ri = (size_t)np_l * 128 * 256 + (size_t)s * 256 + oc;
                    float v = acc[sf][of][r2] + bf2f(resH[ri]) + bf2f(resL[ri]);
                    m = fmaxf(m, v);
                }
            }
            m = fmaxf(m, __shfl_xor(m, 16));
            m = fmaxf(m, __shfl_xor(m, 32));
            if (l < 16) cmax[w >> 1][w & 1][of * 16 + l] = m;
        }
        __syncthreads();
        if (tid < 128){
            int oh = tid >> 6, col = tid & 63;
            float v = fmaxf(cmax[oh][0][col], cmax[oh][1][col]);
            outF[((size_t)p * N_ + n_g) * C_ + o0 + oh * 64 + col] = v;
        }
    }
}

// ---------------------------------------------------------------------------
// Attention per (n,h,p): 3-term split QK^T MFMA (bf16 plane inputs),
// fp32 softmax+colsum (argmax), bf16 PV MFMA; O (bf16 hi) overwrites q-cols.
// Flat grid, XCD-swizzled: 4 heads of one np on the same XCD.
// ---------------------------------------------------------------------------
__global__ __launch_bounds__(256) void attn3(unsigned short* __restrict__ qH,
                                             const unsigned short* __restrict__ qL,
                                             int* __restrict__ idxA, int n0, int cnp){
    __shared__ char smraw[17408 + 34816 + 2048];
    unsigned short* Vs = (unsigned short*)smraw;             // [64][136] bf16
    unsigned short* Pm = (unsigned short*)(smraw + 17408);   // [128][136] bf16
    float* csW = (float*)(smraw + 17408 + 34816);            // [4][128]
    unsigned short* Ot = (unsigned short*)smraw;             // [128][72] bf16 (alias)

    const int id = blockIdx.x;
    const int xcd = id & 7;
    const int r = id >> 3;               // 0 .. 8*cnp - 1
    const int ppl = r / (cnp * 4);
    const int rr = r % (cnp * 4);
    const int n_l = rr >> 2, h = rr & 3;
    const int p = xcd * 2 + ppl;
    const int np_l = n_l * 16 + p;
    const int tid = threadIdx.x, w = tid >> 6, l = tid & 63;
    const int lr = l & 15, lg = l >> 4;
    unsigned short* baseH = qH + (size_t)np_l * 128 * 768;
    const unsigned short* baseL = qL + (size_t)np_l * 128 * 768;

    // stage V: bf16 [t][d] -> Vs[d][t]
#pragma unroll
    for (int it = 0; it < 8; ++it){
        int idx = tid + 256 * it;
        int t = idx >> 4, d4 = (idx & 15) * 4;
        us4 v = *(const us4*)(baseH + (size_t)t * 768 + 512 + h * 64 + d4);
#pragma unroll
        for (int j = 0; j < 4; ++j) Vs[(d4 + j) * 136 + t] = v[j];
    }

    // Q fragments (hi/lo) straight from planes
    short8 qh[2][2], ql[2][2];
#pragma unroll
    for (int sf = 0; sf < 2; ++sf)
#pragma unroll
        for (int ks = 0; ks < 2; ++ks){
            size_t off = (size_t)(w * 32 + sf * 16 + lr) * 768 + h * 64 + ks * 32 + lg * 8;
            qh[sf][ks] = *(const short8*)(baseH + off);
            ql[sf][ks] = *(const short8*)(baseL + off);
        }

    f32x4 dacc[2][8];
#pragma unroll
    for (int i = 0; i < 2; ++i)
#pragma unroll
        for (int j = 0; j < 8; ++j) dacc[i][j] = (f32x4){0.f, 0.f, 0.f, 0.f};

#pragma unroll
    for (int tf = 0; tf < 8; ++tf){
#pragma unroll
        for (int ks = 0; ks < 2; ++ks){
            size_t off = (size_t)(tf * 16 + lr) * 768 + 256 + h * 64 + ks * 32 + lg * 8;
            short8 kh = *(const short8*)(baseH + off);
            short8 kl = *(const short8*)(baseL + off);
#pragma unroll
            for (int sf = 0; sf < 2; ++sf){
                dacc[sf][tf] = __builtin_amdgcn_mfma_f32_16x16x32_bf16(qh[sf][ks], kh, dacc[sf][tf], 0, 0, 0);
                dacc[sf][tf] = __builtin_amdgcn_mfma_f32_16x16x32_bf16(qh[sf][ks], kl, dacc[sf][tf], 0, 0, 0);
                dacc[sf][tf] = __builtin_amdgcn_mfma_f32_16x16x32_bf16(ql[sf][ks], kh, dacc[sf][tf], 0, 0, 0);
            }
        }
    }

    // softmax + write P bf16 + fp32 colsum partials
    float csp[8];
#pragma unroll
    for (int tf = 0; tf < 8; ++tf) csp[tf] = 0.f;
#pragma unroll
    for (int sf = 0; sf < 2; ++sf){
#pragma unroll
        for (int r2 = 0; r2 < 4; ++r2){
            float m = -INFINITY;
#pragma unroll
            for (int tf = 0; tf < 8; ++tf) m = fmaxf(m, dacc[sf][tf][r2]);
            m = fmaxf(m, __shfl_xor(m, 1)); m = fmaxf(m, __shfl_xor(m, 2));
            m = fmaxf(m, __shfl_xor(m, 4)); m = fmaxf(m, __shfl_xor(m, 8));
            float e[8]; float sum = 0.f;
#pragma unroll
            for (int tf = 0; tf < 8; ++tf){
                e[tf] = __expf(0.125f * (dacc[sf][tf][r2] - m)); sum += e[tf];
            }
            sum += __shfl_xor(sum, 1); sum += __shfl_xor(sum, 2);
            sum += __shfl_xor(sum, 4); sum += __shfl_xor(sum, 8);
            float inv = 1.f / sum;
            int s = w * 32 + sf * 16 + lg * 4 + r2;
#pragma unroll
            for (int tf = 0; tf < 8; ++tf){
                float pv = e[tf] * inv;
                Pm[s * 136 + tf * 16 + lr] = f2bf(pv);
                csp[tf] += pv;
            }
        }
    }
#pragma unroll
    for (int tf = 0; tf < 8; ++tf){
        float v = csp[tf];
        v += __shfl_xor(v, 16); v += __shfl_xor(v, 32);
        if (l < 16) csW[w * 128 + tf * 16 + l] = v;
    }
    __syncthreads();

    // PV: D[d][s] = sum_t V[d][t] P[s][t]
    f32x4 oacc[8];
#pragma unroll
    for (int i = 0; i < 8; ++i) oacc[i] = (f32x4){0.f, 0.f, 0.f, 0.f};
#pragma unroll
    for (int ks = 0; ks < 4; ++ks){
        short8 av = *(const short8*)(Vs + (w * 16 + lr) * 136 + ks * 32 + lg * 8);
#pragma unroll
        for (int sf = 0; sf < 8; ++sf){
            short8 bp = *(const short8*)(Pm + (sf * 16 + lr) * 136 + ks * 32 + lg * 8);
            oacc[sf] = __builtin_amdgcn_mfma_f32_16x16x32_bf16(av, bp, oacc[sf], 0, 0, 0);
        }
    }
    __syncthreads();

    // argmax of colsum (fp32) — first occurrence
    if (tid < 64){
        float v0 = csW[tid] + csW[128 + tid] + csW[256 + tid] + csW[384 + tid];
        float v1 = csW[64 + tid] + csW[192 + tid] + csW[320 + tid] + csW[448 + tid];
        float bv; int bi;
        if (v1 > v0){ bv = v1; bi = 64 + tid; } else { bv = v0; bi = tid; }
#pragma unroll
        for (int msk = 1; msk <= 32; msk <<= 1){
            float ov = __shfl_xor(bv, msk); int oi = __shfl_xor(bi, msk);
            if (ov > bv || (ov == bv && oi < bi)){ bv = ov; bi = oi; }
        }
        if (tid == 0){ int n_g = n0 + n_l; idxA[(n_g * H_ + h) * P_ + p] = bi; }
    }

    // O frags -> Ot[s][d] bf16, then coalesced store over q-cols (hi plane)
#pragma unroll
    for (int sf = 0; sf < 8; ++sf){
        int s = sf * 16 + lr;
#pragma unroll
        for (int r2 = 0; r2 < 4; ++r2) Ot[s * 72 + w * 16 + lg * 4 + r2] = f2bf(oacc[sf][r2]);
    }
    __syncthreads();
#pragma unroll
    for (int it = 0; it < 4; ++it){
        int idx = tid + 256 * it;
        int s = idx >> 3, d8 = (idx & 7) * 8;
        *(short8*)(baseH + (size_t)s * 768 + h * 64 + d8) = *(const short8*)(Ot + s * 72 + d8);
    }
}

// ---------------------------------------------------------------------------
__global__ void bn_stats(const float* __restrict__ wpvT,
                         const float* __restrict__ gamma,
                         const float* __restrict__ beta,
                         float* __restrict__ aArr, float* __restrict__ bArr)
{
    int i = blockIdx.x * blockDim.x + threadIdx.x;
    if (i >= P_ * C_) return;
    int p = i / C_, c = i % C_;
    const float* basep = wpvT + (size_t)p * N_ * C_ + c;
    float su = 0.f, s2 = 0.f;
    for (int n = 0; n < N_; ++n){
        float v = basep[n * C_];
        su += v; s2 += v * v;
    }
    float mean = su * (1.f / N_);
    float var = s2 * (1.f / N_) - mean * mean;
    float rstd = rsqrtf(var + 1e-5f);
    float a = gamma[i] * rstd;
    aArr[i] = a;
    bArr[i] = beta[i] - mean * a;
}

// pf[m][c] = bf16(wpvT[m][c]*a + b), m = p*32+n
__global__ __launch_bounds__(256) void pf_kernel(const float* __restrict__ wpvT,
                                                 const float* __restrict__ aArr,
                                                 const float* __restrict__ bArr,
                                                 unsigned short* __restrict__ pfb){
    int m = blockIdx.x, c = threadIdx.x;
    int p = m >> 5;
    float v = wpvT[(size_t)m * 256 + c];
    pfb[(size_t)m * 256 + c] = f2bf(v * aArr[p * 256 + c] + bArr[p * 256 + c]);
}

// cls GEMM: cls[n*16+p][k] = sum_c pf[p*32+n][c] * fcT[k][c]; 1-term bf16
__global__ __launch_bounds__(256) void gemmc(const unsigned short* __restrict__ pfb,
                                             const unsigned short* __restrict__ fcT,
                                             float* __restrict__ cls){
    __shared__ unsigned short sm[2 * 128 * 72];
    unsigned short* AhL = sm;
    unsigned short* BhL = sm + 128 * 72;

    const int tid = threadIdx.x;
    const int w = tid >> 6, l = tid & 63;
    const int lr = l & 15, lg = l >> 4;
    const int ws0 = (w & 1) * 64, wo0 = (w >> 1) * 64;
    const int o0 = blockIdx.x * 128;
    const int m0 = blockIdx.y * 128;

    f32x4 acc[4][4];
#pragma unroll
    for (int i = 0; i < 4; ++i)
#pragma unroll
        for (int j = 0; j < 4; ++j) acc[i][j] = (f32x4){0.f, 0.f, 0.f, 0.f};

    for (int k0 = 0; k0 < 256; k0 += 64){
#pragma unroll
        for (int it = 0; it < 4; ++it){
            int idx = tid + 256 * it;
            int s = idx >> 3, c8 = (idx & 7) * 8;
            *(short8*)(AhL + s * 72 + c8) = *(const short8*)(pfb + (size_t)(m0 + s) * 256 + k0 + c8);
            *(short8*)(BhL + s * 72 + c8) = *(const short8*)(fcT + (size_t)(o0 + s) * 256 + k0 + c8);
        }
        __syncthreads();
#pragma unroll
        for (int ks = 0; ks < 2; ++ks){
            short8 ah[4];
#pragma unroll
            for (int sf = 0; sf < 4; ++sf)
                ah[sf] = *(const short8*)(AhL + (ws0 + sf * 16 + lr) * 72 + ks * 32 + lg * 8);
#pragma unroll
            for (int of = 0; of < 4; ++of){
                short8 bh = *(const short8*)(BhL + (wo0 + of * 16 + lr) * 72 + ks * 32 + lg * 8);
#pragma unroll
                for (int sf = 0; sf < 4; ++sf)
                    acc[sf][of] = __builtin_amdgcn_mfma_f32_16x16x32_bf16(ah[sf], bh, acc[sf][of], 0, 0, 0);
            }
        }
        __syncthreads();
    }
#pragma unroll
    for (int sf = 0; sf < 4; ++sf)
#pragma unroll
        for (int of = 0; of < 4; ++of){
            int oc = o0 + wo0 + of * 16 + lr;
            if (oc < CLS_){
#pragma unroll
                for (int r2 = 0; r2 < 4; ++r2){
                    int m = m0 + ws0 + sf * 16 + lg * 4 + r2;
                    int n = m & 31, p = m >> 5;
                    cls[((size_t)n * 16 + p) * CLS_ + oc] = acc[sf][of][r2];
                }
            }
        }
}

__global__ void sel_kernel(const float* __restrict__ t_f,
                           const int* __restrict__ idxArr,
                           float* __restrict__ selT)
{
    const int np = blockIdx.x;
    const int n = np >> 4, p = np & 15;
    const int c = threadIdx.x;
    float acc = 0.f;
#pragma unroll
    for (int h = 0; h < H_; ++h){
        int s = idxArr[(n * H_ + h) * P_ + p];
        acc += t_f[((size_t)np * C_ + c) * S_ + s];
    }
    selT[((size_t)p * N_ + n) * C_ + c] = acc;
}

// ---------------------------------------------------------------------------
extern "C" void kernel_launch(void* const* d_in, const int* in_sizes, int n_in,
                              void* d_out, int out_size, void* d_ws, size_t ws_size,
                              hipStream_t stream)
{
    const float* t_f     = (const float*)d_in[0];
    const float* t_s     = (const float*)d_in[1];
    const float* t_l     = (const float*)d_in[2];
    const float* decay_w = (const float*)d_in[3];
    const float* qkv_w   = (const float*)d_in[4];
    const float* out_w   = (const float*)d_in[5];
    const float* gamma   = (const float*)d_in[6];
    const float* beta    = (const float*)d_in[7];
    const float* fc      = (const float*)d_in[8];
    float* out = (float*)d_out;

    // ---- ws layout: converted weights at head, then chunked activations ----
    const size_t WD = 3145728, WQ = 3145728, WO = 1048576;
    char* basep = (char*)d_ws;
    unsigned short* wdh = (unsigned short*)basep;
    unsigned short* wdl = wdh + WD;
    unsigned short* wqh = wdl + WD;
    unsigned short* wql = wqh + WQ;
    unsigned short* woh = wql + WQ;
    unsigned short* fcT = woh + WO;            // 3072*256
    unsigned short* pfb = fcT + 3072 * 256;    // 512*256
    float* aArr = (float*)(pfb + 512 * 256);
    float* bArr = aArr + P_ * C_;
    int* idxA = (int*)(bArr + P_ * C_);
    char* big = (char*)(idxA + N_ * H_ * P_);
    size_t head = (size_t)(big - basep);
    size_t avail = (ws_size > head) ? (ws_size - head) : 0;
    const size_t per_n = (size_t)16 * 128 * (768 + 256 + 768) * 2 * 2;  // hi+lo bf16
    int cn = (int)(avail / per_n);
    if (cn < 1) cn = 1;
    if (cn > N_) cn = N_;
    int nch = (N_ + cn - 1) / cn;
    cn = (N_ + nch - 1) / nch;

    unsigned short* xH = (unsigned short*)big;                 // cn*16*128*768
    unsigned short* xL = xH + (size_t)cn * 16 * 128 * 768;
    unsigned short* tH = xL + (size_t)cn * 16 * 128 * 768;     // cn*16*128*256
    unsigned short* tL = tH + (size_t)cn * 16 * 128 * 256;
    unsigned short* qH = tL + (size_t)cn * 16 * 128 * 256;     // cn*16*128*768
    unsigned short* qL = qH + (size_t)cn * 16 * 128 * 768;

    float* cls  = out;
    float* wpvT = out + (size_t)N_ * P_ * CLS_;
    float* selT = wpvT + (size_t)P_ * N_ * C_;

    wsplit<<<2048, 256, 0, stream>>>(decay_w, qkv_w, out_w, wdh, wdl, wqh, wql, woh);
    fct_kernel<<<12, 256, 0, stream>>>(fc, fcT);

    for (int n0 = 0; n0 < N_; n0 += cn){
        int c = (N_ - n0 < cn) ? (N_ - n0) : cn;
        int npg = c * 16;
        xT_kernel<<<dim3(npg, 3), 256, 0, stream>>>(t_f, t_s, t_l, xH, xL, n0);
        gemm3<768, 768, 256, 0, 256><<<npg * 2, 256, 0, stream>>>(
            xH, xL, wdh, wdl, nullptr, nullptr, tH, tL, nullptr, n0, c);
        gemm3<256, 256, 768, 1, 768><<<npg * 6, 256, 0, stream>>>(
            tH, tL, wqh, wql, nullptr, nullptr, qH, qL, nullptr, n0, c);
        attn3<<<c * 64, 256, 0, stream>>>(qH, qL, idxA, n0, c);
        gemm3<256, 768, 256, 2, 256><<<npg * 2, 256, 0, stream>>>(
            qH, qH, woh, woh, tH, tL, nullptr, nullptr, wpvT, n0, c);
    }
    bn_stats<<<(P_ * C_ + 255) / 256, 256, 0, stream>>>(wpvT, gamma, beta, aArr, bArr);
    pf_kernel<<<512, 256, 0, stream>>>(wpvT, aArr, bArr, pfb);
    gemmc<<<dim3(24, 4), 256, 0, stream>>>(pfb, fcT, cls);
    sel_kernel<<<N_ * P_, 256, 0, stream>>>(t_f, idxA, selT);
}

// Round 9
// 439.477 us; speedup vs baseline: 1.7092x; 1.1896x over previous
//
#include <hip/hip_runtime.h>
#include <math.h>

#define N_ 32
#define P_ 16
#define C_ 256
#define S_ 128
#define H_ 4
#define CLS_ 3000

typedef __attribute__((ext_vector_type(4))) float f4v;
typedef __attribute__((ext_vector_type(4))) float f32x4;
typedef __attribute__((ext_vector_type(8))) short short8;
typedef __attribute__((ext_vector_type(4))) unsigned short us4;

__device__ __forceinline__ unsigned short f2bf(float x){
    unsigned u = __float_as_uint(x);
    u += 0x7fffu + ((u >> 16) & 1u);
    return (unsigned short)(u >> 16);
}
__device__ __forceinline__ float bf2f(unsigned short h){
    return __uint_as_float(((unsigned)h) << 16);
}

typedef __attribute__((address_space(1))) const unsigned int gu32_t;
typedef __attribute__((address_space(3))) unsigned int lu32_t;
__device__ __forceinline__ void gload16(const void* g, void* l){
    __builtin_amdgcn_global_load_lds((gu32_t*)g, (lu32_t*)l, 16, 0, 0);
}

// ---------------------------------------------------------------------------
// Split weights fp32 -> bf16 hi/lo (decay_w, qkv_w) and hi-only (out_w)
// ---------------------------------------------------------------------------
__global__ void wsplit(const float* __restrict__ dw, const float* __restrict__ qw,
                       const float* __restrict__ ow,
                       unsigned short* __restrict__ wdh, unsigned short* __restrict__ wdl,
                       unsigned short* __restrict__ wqh, unsigned short* __restrict__ wql,
                       unsigned short* __restrict__ woh){
    int i = blockIdx.x * 256 + threadIdx.x;
    int stride = gridDim.x * 256;
    for (; i < 3145728; i += stride){
        float a = dw[i]; unsigned short h = f2bf(a);
        wdh[i] = h; wdl[i] = f2bf(a - bf2f(h));
        float b = qw[i]; unsigned short h2 = f2bf(b);
        wqh[i] = h2; wql[i] = f2bf(b - bf2f(h2));
        if (i < 1048576) woh[i] = f2bf(ow[i]);
    }
}

// fc [256][3000] fp32 -> fcT [3072][256] bf16 (rows >= 3000 zeroed)
__global__ __launch_bounds__(256) void fct_kernel(const float* __restrict__ fc,
                                                  unsigned short* __restrict__ fcT){
    int n = blockIdx.x * 256 + threadIdx.x;   // 0..3071
    if (n < CLS_){
        for (int c = 0; c < 256; ++c) fcT[(size_t)n * 256 + c] = f2bf(fc[(size_t)c * CLS_ + n]);
    } else {
        for (int c = 0; c < 256; ++c) fcT[(size_t)n * 256 + c] = 0;
    }
}

// ---------------------------------------------------------------------------
// Fused transpose + decay GEMM (3-term split bf16), BK=32:
//   D[s][o] = sum_k x^T[s][k] * decay_w[o][k],  x from raw [np][c][s] layout.
// Per K-step: gload x-chunk [32k][128s] fp32 -> Tf (linear, contiguous rows);
// stage2: thread owns column s (16 scalar reads, 2-way free), converts hi/lo,
// writes swizzled [128][32] A-tiles (chunk ^ ((row>>1)&3)); B via
// source-pre-swizzled gload16. 48 KB LDS -> 3 blocks/CU.
// Epilogue: pitch-136 LDS transpose -> hi/lo planes (OPITCH 256).
// ---------------------------------------------------------------------------
__global__ __launch_bounds__(256) void gemm0t(
    const float* __restrict__ t_f, const float* __restrict__ t_s,
    const float* __restrict__ t_l,
    const unsigned short* __restrict__ Whi, const unsigned short* __restrict__ Wlo,
    unsigned short* __restrict__ outH, unsigned short* __restrict__ outL,
    int n0, int cnp)
{
    __shared__ unsigned short sm[24576];       // 48 KB
    float* Tf = (float*)sm;                    // 4096 f32 (16 KB), linear
    unsigned short* AhL = sm + 8192;           // [128][32] swizzled
    unsigned short* AlL = sm + 12288;
    unsigned short* BhL = sm + 16384;
    unsigned short* BlL = sm + 20480;
    unsigned short* Ep  = sm;                  // epilogue alias (34816 B)

    // XCD-aware flat-grid mapping (OB=2)
    const int id = blockIdx.x;
    const int xcd = id & 7;
    const int r = id >> 3;
    const int ppl = r / (cnp * 2);
    const int rr = r % (cnp * 2);
    const int n_l = rr >> 1;
    const int o_t = rr & 1;
    const int p = xcd * 2 + ppl;
    const int np_l = n_l * 16 + p;
    const int o0 = o_t * 128;
    const size_t np_g = (size_t)(n0 + n_l) * 16 + p;

    const int tid = threadIdx.x;
    const int w = tid >> 6, l = tid & 63;
    const int lr = l & 15, lg = l >> 4;
    const int ws0 = (w & 1) * 64, wo0 = (w >> 1) * 64;
    const int s2 = tid & 127, khalf = tid >> 7;

    const unsigned short* Wp_h = Whi + ((size_t)p * 256 + o0) * 768;
    const unsigned short* Wp_l = Wlo + ((size_t)p * 256 + o0) * 768;

    f32x4 acc[4][4];
#pragma unroll
    for (int i = 0; i < 4; ++i)
#pragma unroll
        for (int j = 0; j < 4; ++j) acc[i][j] = (f32x4){0.f, 0.f, 0.f, 0.f};

    for (int k0 = 0; k0 < 768; k0 += 32){
        const int t = k0 >> 8;
        const float* src = (t == 0) ? t_f : ((t == 1) ? t_s : t_l);
        const float* xbase = src + (np_g * 256 + (k0 & 255)) * 128;
        // stage1: x-chunk -> Tf (linear), W chunks -> B tiles (pre-swizzled src)
#pragma unroll
        for (int it = 0; it < 4; ++it){
            int lin = (w * 4 + it) * 64 + l;           // 0..1023
            gload16(xbase + lin * 4, Tf + lin * 4);
        }
#pragma unroll
        for (int it = 0; it < 2; ++it){
            int lin = (w * 2 + it) * 64 + l;           // 0..511
            int row = lin >> 2, ch = lin & 3;
            int sk = ((ch ^ ((row >> 1) & 3)) << 3);
            gload16(Wp_h + (size_t)row * 768 + k0 + sk, BhL + lin * 8);
            gload16(Wp_l + (size_t)row * 768 + k0 + sk, BlL + lin * 8);
        }
        __syncthreads();
        // stage2: column s2, 16 k values -> hi/lo short8, swizzled A-tiles
        {
            short8 h0, h1, l0, l1;
#pragma unroll
            for (int j = 0; j < 8; ++j){
                float v = Tf[(khalf * 16 + j) * 128 + s2];
                unsigned short hh = f2bf(v);
                h0[j] = (short)hh; l0[j] = (short)f2bf(v - bf2f(hh));
            }
#pragma unroll
            for (int j = 0; j < 8; ++j){
                float v = Tf[(khalf * 16 + 8 + j) * 128 + s2];
                unsigned short hh = f2bf(v);
                h1[j] = (short)hh; l1[j] = (short)f2bf(v - bf2f(hh));
            }
            int sb = (s2 >> 1) & 3;
            int c0 = (khalf * 2) ^ sb, c1 = (khalf * 2 + 1) ^ sb;
            *(short8*)(AhL + s2 * 32 + c0 * 8) = h0;
            *(short8*)(AhL + s2 * 32 + c1 * 8) = h1;
            *(short8*)(AlL + s2 * 32 + c0 * 8) = l0;
            *(short8*)(AlL + s2 * 32 + c1 * 8) = l1;
        }
        __syncthreads();
        // MFMA (one K=32 slab, 3-term)
        short8 ah[4], al[4];
#pragma unroll
        for (int sf = 0; sf < 4; ++sf){
            int row = ws0 + sf * 16 + lr;
            int cof = (lg ^ ((row >> 1) & 3)) << 3;
            ah[sf] = *(const short8*)(AhL + row * 32 + cof);
            al[sf] = *(const short8*)(AlL + row * 32 + cof);
        }
#pragma unroll
        for (int of = 0; of < 4; ++of){
            int row = wo0 + of * 16 + lr;
            int cof = (lg ^ ((row >> 1) & 3)) << 3;
            short8 bh = *(const short8*)(BhL + row * 32 + cof);
            short8 bl = *(const short8*)(BlL + row * 32 + cof);
#pragma unroll
            for (int sf = 0; sf < 4; ++sf){
                acc[sf][of] = __builtin_amdgcn_mfma_f32_16x16x32_bf16(ah[sf], bh, acc[sf][of], 0, 0, 0);
                acc[sf][of] = __builtin_amdgcn_mfma_f32_16x16x32_bf16(ah[sf], bl, acc[sf][of], 0, 0, 0);
                acc[sf][of] = __builtin_amdgcn_mfma_f32_16x16x32_bf16(al[sf], bh, acc[sf][of], 0, 0, 0);
            }
        }
        __syncthreads();
    }

    // epilogue: pitch-136 LDS transpose -> hi/lo planes
#pragma unroll
    for (int plane = 0; plane < 2; ++plane){
#pragma unroll
        for (int sf = 0; sf < 4; ++sf)
#pragma unroll
            for (int of = 0; of < 4; ++of){
                int col = wo0 + of * 16 + lr;
#pragma unroll
                for (int r2 = 0; r2 < 4; ++r2){
                    int row = ws0 + sf * 16 + lg * 4 + r2;
                    float v = acc[sf][of][r2];
                    unsigned short hh = f2bf(v);
                    unsigned short q = plane ? f2bf(v - bf2f(hh)) : hh;
                    Ep[row * 136 + col] = q;
                }
            }
        __syncthreads();
        unsigned short* dst = plane ? outL : outH;
#pragma unroll
        for (int it = 0; it < 8; ++it){
            int idx = tid + 256 * it;
            int row = idx >> 4, seg = (idx & 15) * 8;
            *(short8*)(dst + (size_t)np_l * 128 * 256 + (size_t)row * 256 + o0 + seg) =
                *(const short8*)(Ep + row * 136 + seg);
        }
        __syncthreads();
    }
}

// ---------------------------------------------------------------------------
// Split-bf16 MFMA GEMM (round-5 K-loop):  D[s][o] = sum_k A[s][k] * W[o][k]
// Staging: global_load_lds(16) into linear [128][64]-short tiles, 16B-chunk
// XOR-swizzled by (row&7) on the SOURCE address; frag reads apply same XOR.
// Flat grid, XCD-swizzled. MODE 1 (3-term): hi/lo planes via pitch-136
// LDS-transpose epilogue. MODE 2 (1-term): wpv epilogue (residual+max).
// ---------------------------------------------------------------------------
template<int KEXT, int APITCH, int ND, int MODE, int OPITCH>
__global__ __launch_bounds__(256) void gemm3(
    const unsigned short* __restrict__ Ah_g, const unsigned short* __restrict__ Al_g,
    const unsigned short* __restrict__ Whi, const unsigned short* __restrict__ Wlo,
    const unsigned short* __restrict__ resH, const unsigned short* __restrict__ resL,
    unsigned short* __restrict__ outH, unsigned short* __restrict__ outL,
    float* __restrict__ outF, int n0, int cnp)
{
    constexpr int T3 = (MODE == 2) ? 0 : 1;
    constexpr int OB = ND / 128;
    __shared__ unsigned short sm[(T3 ? 4 : 2) * 128 * 64];
    unsigned short* AhL = sm;
    unsigned short* BhL = sm + 8192;
    unsigned short* AlL = T3 ? (sm + 16384) : sm;
    unsigned short* BlL = T3 ? (sm + 24576) : sm;
    unsigned short* Ep = sm;   // epilogue alias (34816 B <= 65536 B, T3 only)
    __shared__ float cmax[2][2][64];

    // --- XCD-aware flat-grid mapping ---
    const int id = blockIdx.x;
    const int xcd = id & 7;
    const int r = id >> 3;               // 0 .. 2*cnp*OB - 1
    const int ppl = r / (cnp * OB);
    const int rr = r % (cnp * OB);
    const int n_l = rr / OB;
    const int o_t = rr % OB;
    const int p = xcd * 2 + ppl;
    const int np_l = n_l * 16 + p;
    const int o0 = o_t * 128;

    const int tid = threadIdx.x;
    const int w = tid >> 6, l = tid & 63;
    const int lr = l & 15, lg = l >> 4;
    const int ws0 = (w & 1) * 64, wo0 = (w >> 1) * 64;
    const size_t aBase = (size_t)np_l * 128 * APITCH;
    const unsigned short* Wp_h = Whi + ((size_t)p * ND + o0) * KEXT;
    const unsigned short* Wp_l = T3 ? (Wlo + ((size_t)p * ND + o0) * KEXT) : Wp_h;

    f32x4 acc[4][4];
#pragma unroll
    for (int i = 0; i < 4; ++i)
#pragma unroll
        for (int j = 0; j < 4; ++j) acc[i][j] = (f32x4){0.f, 0.f, 0.f, 0.f};

    for (int k0 = 0; k0 < KEXT; k0 += 64){
#pragma unroll
        for (int it = 0; it < 4; ++it){
            int slot = w * 4 + it;
            int lin = slot * 64 + l;
            int row = lin >> 3, chnk = lin & 7;
            int sk = ((chnk ^ (row & 7)) << 3);
            unsigned short* ldst = sm + slot * 512;
            const unsigned short* ga = Ah_g + aBase + (size_t)row * APITCH + k0 + sk;
            gload16(ga, ldst);
            const unsigned short* gb = Wp_h + (size_t)row * KEXT + k0 + sk;
            gload16(gb, ldst + 8192);
            if (T3){
                gload16(Al_g + aBase + (size_t)row * APITCH + k0 + sk, ldst + 16384);
                gload16(Wp_l + (size_t)row * KEXT + k0 + sk, ldst + 24576);
            }
        }
        __syncthreads();
#pragma unroll
        for (int ks = 0; ks < 2; ++ks){
            short8 ah[4], al[4];
#pragma unroll
            for (int sf = 0; sf < 4; ++sf){
                int row = ws0 + sf * 16 + lr;
                int cof = ((ks * 4 + lg) ^ (row & 7)) << 3;
                ah[sf] = *(const short8*)(AhL + row * 64 + cof);
                if (T3) al[sf] = *(const short8*)(AlL + row * 64 + cof);
            }
#pragma unroll
            for (int of = 0; of < 4; ++of){
                int row = wo0 + of * 16 + lr;
                int cof = ((ks * 4 + lg) ^ (row & 7)) << 3;
                short8 bh = *(const short8*)(BhL + row * 64 + cof);
                short8 bl = bh;
                if (T3) bl = *(const short8*)(BlL + row * 64 + cof);
#pragma unroll
                for (int sf = 0; sf < 4; ++sf){
                    acc[sf][of] = __builtin_amdgcn_mfma_f32_16x16x32_bf16(ah[sf], bh, acc[sf][of], 0, 0, 0);
                    if (T3){
                        acc[sf][of] = __builtin_amdgcn_mfma_f32_16x16x32_bf16(ah[sf], bl, acc[sf][of], 0, 0, 0);
                        acc[sf][of] = __builtin_amdgcn_mfma_f32_16x16x32_bf16(al[sf], bh, acc[sf][of], 0, 0, 0);
                    }
                }
            }
        }
        __syncthreads();
    }

    if (MODE != 2){
#pragma unroll
        for (int plane = 0; plane < 2; ++plane){
#pragma unroll
            for (int sf = 0; sf < 4; ++sf)
#pragma unroll
                for (int of = 0; of < 4; ++of){
                    int col = wo0 + of * 16 + lr;
#pragma unroll
                    for (int r2 = 0; r2 < 4; ++r2){
                        int row = ws0 + sf * 16 + lg * 4 + r2;
                        float v = acc[sf][of][r2];
                        unsigned short hh = f2bf(v);
                        unsigned short q = plane ? f2bf(v - bf2f(hh)) : hh;
                        Ep[row * 136 + col] = q;
                    }
                }
            __syncthreads();
            unsigned short* dst = plane ? outL : outH;
#pragma unroll
            for (int it = 0; it < 8; ++it){
                int idx = tid + 256 * it;
                int row = idx >> 4, seg = (idx & 15) * 8;
                *(short8*)(dst + (size_t)np_l * 128 * OPITCH + (size_t)row * OPITCH + o0 + seg) =
                    *(const short8*)(Ep + row * 136 + seg);
            }
            __syncthreads();
        }
    } else {
        const int n_g = n0 + n_l;
#pragma unroll
        for (int of = 0; of < 4; ++of){
            int oc = o0 + wo0 + of * 16 + lr;
            float m = -INFINITY;
#pragma unroll
            for (int sf = 0; sf < 4; ++sf){
#pragma unroll
                for (int r2 = 0; r2 < 4; ++r2){
                    int s = ws0 + sf * 16 + lg * 4 + r2;
                    size_t ri = (size_t)np_l * 128 * 256 + (size_t)s * 256 + oc;
                    float v = acc[sf][of][r2] + bf2f(resH[ri]) + bf2f(resL[ri]);
                    m = fmaxf(m, v);
                }
            }
            m = fmaxf(m, __shfl_xor(m, 16));
            m = fmaxf(m, __shfl_xor(m, 32));
            if (l < 16) cmax[w >> 1][w & 1][of * 16 + l] = m;
        }
        __syncthreads();
        if (tid < 128){
            int oh = tid >> 6, col = tid & 63;
            float v = fmaxf(cmax[oh][0][col], cmax[oh][1][col]);
            outF[((size_t)p * N_ + n_g) * C_ + o0 + oh * 64 + col] = v;
        }
    }
}

// ---------------------------------------------------------------------------
// Attention per (n,h,p): 3-term split QK^T MFMA (bf16 plane inputs),
// fp32 softmax+colsum (argmax), bf16 PV MFMA; O (bf16 hi) overwrites q-cols.
// Flat grid, XCD-swizzled: 4 heads of one np on the same XCD.
// ---------------------------------------------------------------------------
__global__ __launch_bounds__(256) void attn3(unsigned short* __restrict__ qH,
                                             const unsigned short* __restrict__ qL,
                                             int* __restrict__ idxA, int n0, int cnp){
    __shared__ char smraw[17408 + 34816 + 2048];
    unsigned short* Vs = (unsigned short*)smraw;             // [64][136] bf16
    unsigned short* Pm = (unsigned short*)(smraw + 17408);   // [128][136] bf16
    float* csW = (float*)(smraw + 17408 + 34816);            // [4][128]
    unsigned short* Ot = (unsigned short*)smraw;             // [128][72] bf16 (alias)

    const int id = blockIdx.x;
    const int xcd = id & 7;
    const int r = id >> 3;               // 0 .. 8*cnp - 1
    const int ppl = r / (cnp * 4);
    const int rr = r % (cnp * 4);
    const int n_l = rr >> 2, h = rr & 3;
    const int p = xcd * 2 + ppl;
    const int np_l = n_l * 16 + p;
    const int tid = threadIdx.x, w = tid >> 6, l = tid & 63;
    const int lr = l & 15, lg = l >> 4;
    unsigned short* baseH = qH + (size_t)np_l * 128 * 768;
    const unsigned short* baseL = qL + (size_t)np_l * 128 * 768;

    // stage V: bf16 [t][d] -> Vs[d][t]
#pragma unroll
    for (int it = 0; it < 8; ++it){
        int idx = tid + 256 * it;
        int t = idx >> 4, d4 = (idx & 15) * 4;
        us4 v = *(const us4*)(baseH + (size_t)t * 768 + 512 + h * 64 + d4);
#pragma unroll
        for (int j = 0; j < 4; ++j) Vs[(d4 + j) * 136 + t] = v[j];
    }

    // Q fragments (hi/lo) straight from planes
    short8 qh[2][2], ql[2][2];
#pragma unroll
    for (int sf = 0; sf < 2; ++sf)
#pragma unroll
        for (int ks = 0; ks < 2; ++ks){
            size_t off = (size_t)(w * 32 + sf * 16 + lr) * 768 + h * 64 + ks * 32 + lg * 8;
            qh[sf][ks] = *(const short8*)(baseH + off);
            ql[sf][ks] = *(const short8*)(baseL + off);
        }

    f32x4 dacc[2][8];
#pragma unroll
    for (int i = 0; i < 2; ++i)
#pragma unroll
        for (int j = 0; j < 8; ++j) dacc[i][j] = (f32x4){0.f, 0.f, 0.f, 0.f};

#pragma unroll
    for (int tf = 0; tf < 8; ++tf){
#pragma unroll
        for (int ks = 0; ks < 2; ++ks){
            size_t off = (size_t)(tf * 16 + lr) * 768 + 256 + h * 64 + ks * 32 + lg * 8;
            short8 kh = *(const short8*)(baseH + off);
            short8 kl = *(const short8*)(baseL + off);
#pragma unroll
            for (int sf = 0; sf < 2; ++sf){
                dacc[sf][tf] = __builtin_amdgcn_mfma_f32_16x16x32_bf16(qh[sf][ks], kh, dacc[sf][tf], 0, 0, 0);
                dacc[sf][tf] = __builtin_amdgcn_mfma_f32_16x16x32_bf16(qh[sf][ks], kl, dacc[sf][tf], 0, 0, 0);
                dacc[sf][tf] = __builtin_amdgcn_mfma_f32_16x16x32_bf16(ql[sf][ks], kh, dacc[sf][tf], 0, 0, 0);
            }
        }
    }

    // softmax + write P bf16 + fp32 colsum partials
    float csp[8];
#pragma unroll
    for (int tf = 0; tf < 8; ++tf) csp[tf] = 0.f;
#pragma unroll
    for (int sf = 0; sf < 2; ++sf){
#pragma unroll
        for (int r2 = 0; r2 < 4; ++r2){
            float m = -INFINITY;
#pragma unroll
            for (int tf = 0; tf < 8; ++tf) m = fmaxf(m, dacc[sf][tf][r2]);
            m = fmaxf(m, __shfl_xor(m, 1)); m = fmaxf(m, __shfl_xor(m, 2));
            m = fmaxf(m, __shfl_xor(m, 4)); m = fmaxf(m, __shfl_xor(m, 8));
            float e[8]; float sum = 0.f;
#pragma unroll
            for (int tf = 0; tf < 8; ++tf){
                e[tf] = __expf(0.125f * (dacc[sf][tf][r2] - m)); sum += e[tf];
            }
            sum += __shfl_xor(sum, 1); sum += __shfl_xor(sum, 2);
            sum += __shfl_xor(sum, 4); sum += __shfl_xor(sum, 8);
            float inv = 1.f / sum;
            int s = w * 32 + sf * 16 + lg * 4 + r2;
#pragma unroll
            for (int tf = 0; tf < 8; ++tf){
                float pv = e[tf] * inv;
                Pm[s * 136 + tf * 16 + lr] = f2bf(pv);
                csp[tf] += pv;
            }
        }
    }
#pragma unroll
    for (int tf = 0; tf < 8; ++tf){
        float v = csp[tf];
        v += __shfl_xor(v, 16); v += __shfl_xor(v, 32);
        if (l < 16) csW[w * 128 + tf * 16 + l] = v;
    }
    __syncthreads();

    // PV: D[d][s] = sum_t V[d][t] P[s][t]
    f32x4 oacc[8];
#pragma unroll
    for (int i = 0; i < 8; ++i) oacc[i] = (f32x4){0.f, 0.f, 0.f, 0.f};
#pragma unroll
    for (int ks = 0; ks < 4; ++ks){
        short8 av = *(const short8*)(Vs + (w * 16 + lr) * 136 + ks * 32 + lg * 8);
#pragma unroll
        for (int sf = 0; sf < 8; ++sf){
            short8 bp = *(const short8*)(Pm + (sf * 16 + lr) * 136 + ks * 32 + lg * 8);
            oacc[sf] = __builtin_amdgcn_mfma_f32_16x16x32_bf16(av, bp, oacc[sf], 0, 0, 0);
        }
    }
    __syncthreads();

    // argmax of colsum (fp32) — first occurrence
    if (tid < 64){
        float v0 = csW[tid] + csW[128 + tid] + csW[256 + tid] + csW[384 + tid];
        float v1 = csW[64 + tid] + csW[192 + tid] + csW[320 + tid] + csW[448 + tid];
        float bv; int bi;
        if (v1 > v0){ bv = v1; bi = 64 + tid; } else { bv = v0; bi = tid; }
#pragma unroll
        for (int msk = 1; msk <= 32; msk <<= 1){
            float ov = __shfl_xor(bv, msk); int oi = __shfl_xor(bi, msk);
            if (ov > bv || (ov == bv && oi < bi)){ bv = ov; bi = oi; }
        }
        if (tid == 0){ int n_g = n0 + n_l; idxA[(n_g * H_ + h) * P_ + p] = bi; }
    }

    // O frags -> Ot[s][d] bf16, then coalesced store over q-cols (hi plane)
#pragma unroll
    for (int sf = 0; sf < 8; ++sf){
        int s = sf * 16 + lr;
#pragma unroll
        for (int r2 = 0; r2 < 4; ++r2) Ot[s * 72 + w * 16 + lg * 4 + r2] = f2bf(oacc[sf][r2]);
    }
    __syncthreads();
#pragma unroll
    for (int it = 0; it < 4; ++it){
        int idx = tid + 256 * it;
        int s = idx >> 3, d8 = (idx & 7) * 8;
        *(short8*)(baseH + (size_t)s * 768 + h * 64 + d8) = *(const short8*)(Ot + s * 72 + d8);
    }
}

// ---------------------------------------------------------------------------
__global__ void bn_stats(const float* __restrict__ wpvT,
                         const float* __restrict__ gamma,
                         const float* __restrict__ beta,
                         float* __restrict__ aArr, float* __restrict__ bArr)
{
    int i = blockIdx.x * blockDim.x + threadIdx.x;
    if (i >= P_ * C_) return;
    int p = i / C_, c = i % C_;
    const float* basep = wpvT + (size_t)p * N_ * C_ + c;
    float su = 0.f, s2 = 0.f;
    for (int n = 0; n < N_; ++n){
        float v = basep[n * C_];
        su += v; s2 += v * v;
    }
    float mean = su * (1.f / N_);
    float var = s2 * (1.f / N_) - mean * mean;
    float rstd = rsqrtf(var + 1e-5f);
    float a = gamma[i] * rstd;
    aArr[i] = a;
    bArr[i] = beta[i] - mean * a;
}

// pf[m][c] = bf16(wpvT[m][c]*a + b), m = p*32+n
__global__ __launch_bounds__(256) void pf_kernel(const float* __restrict__ wpvT,
                                                 const float* __restrict__ aArr,
                                                 const float* __restrict__ bArr,
                                                 unsigned short* __restrict__ pfb){
    int m = blockIdx.x, c = threadIdx.x;
    int p = m >> 5;
    float v = wpvT[(size_t)m * 256 + c];
    pfb[(size_t)m * 256 + c] = f2bf(v * aArr[p * 256 + c] + bArr[p * 256 + c]);
}

// cls GEMM: cls[n*16+p][k] = sum_c pf[p*32+n][c] * fcT[k][c]; 1-term bf16
__global__ __launch_bounds__(256) void gemmc(const unsigned short* __restrict__ pfb,
                                             const unsigned short* __restrict__ fcT,
                                             float* __restrict__ cls){
    __shared__ unsigned short sm[2 * 128 * 72];
    unsigned short* AhL = sm;
    unsigned short* BhL = sm + 128 * 72;

    const int tid = threadIdx.x;
    const int w = tid >> 6, l = tid & 63;
    const int lr = l & 15, lg = l >> 4;
    const int ws0 = (w & 1) * 64, wo0 = (w >> 1) * 64;
    const int o0 = blockIdx.x * 128;
    const int m0 = blockIdx.y * 128;

    f32x4 acc[4][4];
#pragma unroll
    for (int i = 0; i < 4; ++i)
#pragma unroll
        for (int j = 0; j < 4; ++j) acc[i][j] = (f32x4){0.f, 0.f, 0.f, 0.f};

    for (int k0 = 0; k0 < 256; k0 += 64){
#pragma unroll
        for (int it = 0; it < 4; ++it){
            int idx = tid + 256 * it;
            int s = idx >> 3, c8 = (idx & 7) * 8;
            *(short8*)(AhL + s * 72 + c8) = *(const short8*)(pfb + (size_t)(m0 + s) * 256 + k0 + c8);
            *(short8*)(BhL + s * 72 + c8) = *(const short8*)(fcT + (size_t)(o0 + s) * 256 + k0 + c8);
        }
        __syncthreads();
#pragma unroll
        for (int ks = 0; ks < 2; ++ks){
            short8 ah[4];
#pragma unroll
            for (int sf = 0; sf < 4; ++sf)
                ah[sf] = *(const short8*)(AhL + (ws0 + sf * 16 + lr) * 72 + ks * 32 + lg * 8);
#pragma unroll
            for (int of = 0; of < 4; ++of){
                short8 bh = *(const short8*)(BhL + (wo0 + of * 16 + lr) * 72 + ks * 32 + lg * 8);
#pragma unroll
                for (int sf = 0; sf < 4; ++sf)
                    acc[sf][of] = __builtin_amdgcn_mfma_f32_16x16x32_bf16(ah[sf], bh, acc[sf][of], 0, 0, 0);
            }
        }
        __syncthreads();
    }
#pragma unroll
    for (int sf = 0; sf < 4; ++sf)
#pragma unroll
        for (int of = 0; of < 4; ++of){
            int oc = o0 + wo0 + of * 16 + lr;
            if (oc < CLS_){
#pragma unroll
                for (int r2 = 0; r2 < 4; ++r2){
                    int m = m0 + ws0 + sf * 16 + lg * 4 + r2;
                    int n = m & 31, p = m >> 5;
                    cls[((size_t)n * 16 + p) * CLS_ + oc] = acc[sf][of][r2];
                }
            }
        }
}

__global__ void sel_kernel(const float* __restrict__ t_f,
                           const int* __restrict__ idxArr,
                           float* __restrict__ selT)
{
    const int np = blockIdx.x;
    const int n = np >> 4, p = np & 15;
    const int c = threadIdx.x;
    float acc = 0.f;
#pragma unroll
    for (int h = 0; h < H_; ++h){
        int s = idxArr[(n * H_ + h) * P_ + p];
        acc += t_f[((size_t)np * C_ + c) * S_ + s];
    }
    selT[((size_t)p * N_ + n) * C_ + c] = acc;
}

// ---------------------------------------------------------------------------
extern "C" void kernel_launch(void* const* d_in, const int* in_sizes, int n_in,
                              void* d_out, int out_size, void* d_ws, size_t ws_size,
                              hipStream_t stream)
{
    const float* t_f     = (const float*)d_in[0];
    const float* t_s     = (const float*)d_in[1];
    const float* t_l     = (const float*)d_in[2];
    const float* decay_w = (const float*)d_in[3];
    const float* qkv_w   = (const float*)d_in[4];
    const float* out_w   = (const float*)d_in[5];
    const float* gamma   = (const float*)d_in[6];
    const float* beta    = (const float*)d_in[7];
    const float* fc      = (const float*)d_in[8];
    float* out = (float*)d_out;

    // ---- ws layout: converted weights at head, then chunked activations ----
    const size_t WD = 3145728, WQ = 3145728, WO = 1048576;
    char* basep = (char*)d_ws;
    unsigned short* wdh = (unsigned short*)basep;
    unsigned short* wdl = wdh + WD;
    unsigned short* wqh = wdl + WD;
    unsigned short* wql = wqh + WQ;
    unsigned short* woh = wql + WQ;
    unsigned short* fcT = woh + WO;            // 3072*256
    unsigned short* pfb = fcT + 3072 * 256;    // 512*256
    float* aArr = (float*)(pfb + 512 * 256);
    float* bArr = aArr + P_ * C_;
    int* idxA = (int*)(bArr + P_ * C_);
    char* big = (char*)(idxA + N_ * H_ * P_);
    size_t head = (size_t)(big - basep);
    size_t avail = (ws_size > head) ? (ws_size - head) : 0;
    const size_t per_n = (size_t)16 * 128 * (256 + 768) * 2 * 2;  // tH/tL + qH/qL
    int cn = (int)(avail / per_n);
    if (cn < 1) cn = 1;
    if (cn > N_) cn = N_;
    int nch = (N_ + cn - 1) / cn;
    cn = (N_ + nch - 1) / nch;

    unsigned short* tH = (unsigned short*)big;                 // cn*16*128*256
    unsigned short* tL = tH + (size_t)cn * 16 * 128 * 256;
    unsigned short* qH = tL + (size_t)cn * 16 * 128 * 256;     // cn*16*128*768
    unsigned short* qL = qH + (size_t)cn * 16 * 128 * 768;

    float* cls  = out;
    float* wpvT = out + (size_t)N_ * P_ * CLS_;
    float* selT = wpvT + (size_t)P_ * N_ * C_;

    wsplit<<<2048, 256, 0, stream>>>(decay_w, qkv_w, out_w, wdh, wdl, wqh, wql, woh);
    fct_kernel<<<12, 256, 0, stream>>>(fc, fcT);

    for (int n0 = 0; n0 < N_; n0 += cn){
        int c = (N_ - n0 < cn) ? (N_ - n0) : cn;
        int npg = c * 16;
        gemm0t<<<npg * 2, 256, 0, stream>>>(
            t_f, t_s, t_l, wdh, wdl, tH, tL, n0, c);
        gemm3<256, 256, 768, 1, 768><<<npg * 6, 256, 0, stream>>>(
            tH, tL, wqh, wql, nullptr, nullptr, qH, qL, nullptr, n0, c);
        attn3<<<c * 64, 256, 0, stream>>>(qH, qL, idxA, n0, c);
        gemm3<256, 768, 256, 2, 256><<<npg * 2, 256, 0, stream>>>(
            qH, qH, woh, woh, tH, tL, nullptr, nullptr, wpvT, n0, c);
    }
    bn_stats<<<(P_ * C_ + 255) / 256, 256, 0, stream>>>(wpvT, gamma, beta, aArr, bArr);
    pf_kernel<<<512, 256, 0, stream>>>(wpvT, aArr, bArr, pfb);
    gemmc<<<dim3(24, 4), 256, 0, stream>>>(pfb, fcT, cls);
    sel_kernel<<<N_ * P_, 256, 0, stream>>>(t_f, idxA, selT);
}